// Round 1
// baseline (102.873 us; speedup 1.0000x reference)
//
#include <hip/hip_runtime.h>

// B=16, C=3, H=256, W=256 fp32. 48 slices of 256x256.
// out = inverted, per-slice max-normalized, per-channel-weighted exact EDT.
//
// Pipeline (2 launches, fused epilogue, no fallback kernel):
//   K1: wave per row -> four 64-bit zero-ballots per row (bitmask, 32 B/row)
//       into d_ws (+4096). Block 0 also zeroes the 128-uint control region
//       (slice maxes [0..47], slice counters [64..111]) -- re-poison safe.
//   K2f: per 16-col strip: slice bitmask (8 KB) -> LDS; g^2 in-LDS via
//       clz/ctz nearest-zero search; +-16 windowed min-plus; per-pixel EXACT
//       fallback (full 256-row column rescan) whenever windowed min > 288.
//       d2 stays in registers. Block max -> device-scope atomicMax(slice),
//       release-counter++, acquire-spin until all 16 strips posted, then
//       epilogue out = (mx - w*sqrt(d2))/mx written directly (only output
//       traffic). Deadlock-free: __launch_bounds__(256,3) => 3 blocks/CU
//       (LDS 26.7KB allows 5), grid 768 = 256 CU * 3 -> all co-resident.

#define PADV 1e30f

// ---------------- K1: row bitmask via ballots + ctrl zeroing ----------------
// One wave per row. Lane l holds cols 4l..4l+3; bz[cc] bit l = (col 4l+cc == 0).
__global__ __launch_bounds__(256) void k1_bitmask(const float* __restrict__ in,
                                                  unsigned long long* __restrict__ bits,
                                                  unsigned* __restrict__ ctrl) {
    if (blockIdx.x == 0 && threadIdx.x < 128) ctrl[threadIdx.x] = 0u;

    int row = blockIdx.x * 4 + (threadIdx.x >> 6);
    int lane = threadIdx.x & 63;
    const float4 m = ((const float4*)in)[(long)row * 64 + lane];

    unsigned long long b0 = __ballot(m.x == 0.f);
    unsigned long long b1 = __ballot(m.y == 0.f);
    unsigned long long b2 = __ballot(m.z == 0.f);
    unsigned long long b3 = __ballot(m.w == 0.f);
    if (lane == 0) {
        ulonglong4* dst = (ulonglong4*)(bits + (long)row * 4);
        ulonglong4 v; v.x = b0; v.y = b1; v.z = b2; v.w = b3;
        *dst = v;
    }
}

// ---------------- K2f: g2 + exact min-plus + fused epilogue -----------------
// Block = 256 threads = one slice's 16-col strip (grid 48*16).
// LDS: slice bitmask (256 rows x 4 ull = 8 KB) + column-major g2 tile with
// stride 289 (odd -> benign banking) and 16 pad rows each side.
__global__ __launch_bounds__(256, 3) void k2_fused(const unsigned long long* __restrict__ bits,
                                                   float* __restrict__ out,
                                                   unsigned* __restrict__ ctrl) {
    __shared__ unsigned long long bm[1024];   // [row*4 + cc]
    __shared__ float tile[16 * 289];
    __shared__ float wm[4];
    __shared__ float sMx;
    int bx = blockIdx.x;
    int slice = bx >> 4;
    int w0 = (bx & 15) * 16;
    int tid = threadIdx.x;

    // load slice bitmask: 1024 ull, coalesced
    {
        const unsigned long long* src = bits + (long)slice * 1024;
        #pragma unroll
        for (int i = 0; i < 4; ++i) bm[i * 256 + tid] = src[i * 256 + tid];
    }
    // pad rows of the tile
    {
        int cc = tid >> 4, i = tid & 15;
        tile[cc * 289 + i] = PADV;
        tile[cc * 289 + 272 + i] = PADV;
    }
    __syncthreads();

    int c = tid & 15;                 // column within strip
    int p = w0 + c;                   // global column 0..255
    int rg = tid >> 4;                // 0..15

    // nearest-zero squared distance for (row, col p) from LDS bitmask
    auto nz2 = [&](int row) -> float {
        int dist = 512;               // BIG cap (H+W), matches reference
        #pragma unroll
        for (int cc = 0; cc < 4; ++cc) {
            unsigned long long M = bm[row * 4 + cc];
            int q = p - cc;                          // >= -3
            int qa = (q < 0) ? 0 : q;
            int tp = qa >> 2;                        // floor(q/4) for q>=0
            unsigned long long Ml = (q >= 0) ? (M & (~0ull >> (63 - tp))) : 0ull;
            int tn = (q < 0) ? 0 : ((q + 3) >> 2);   // ceil(q/4)
            unsigned long long Mh = (tn < 64) ? (M & (~0ull << tn)) : 0ull;
            if (Ml) dist = min(dist, q - 4 * (63 - __builtin_clzll(Ml)));
            if (Mh) dist = min(dist, 4 * __builtin_ctzll(Mh) - q);
        }
        float fd = (float)dist;
        return fd * fd;
    };

    // compute g2 for 16 rows (strided assignment: rows rg, rg+16, ... -> <=2-way
    // bank alias on tile writes; bm reads are wave-broadcast per rgroup)
    #pragma unroll
    for (int k = 0; k < 16; ++k) {
        int r = rg + 16 * k;
        tile[c * 289 + 16 + r] = nz2(r);
    }
    __syncthreads();

    // window pass: contiguous ownership rows r0..r0+15
    int r0 = rg * 16;
    float s[48];                       // rows r0-16 .. r0+31 of column c
    #pragma unroll
    for (int i = 0; i < 48; ++i) s[i] = tile[c * 289 + r0 + i];

    float dmin[16];
    #pragma unroll
    for (int k = 0; k < 16; ++k) dmin[k] = s[k + 16];   // o = 0
    #pragma unroll
    for (int o = -16; o <= 16; ++o) {
        if (o == 0) continue;
        float oo = (float)(o * o);
        #pragma unroll
        for (int k = 0; k < 16; ++k)
            dmin[k] = fminf(dmin[k], s[k + 16 + o] + oo);
    }

    // per-pixel exact fallback: windowed min > 288 can't certify optimality
    // within +-16; rescan the full column (already in LDS). Never taken for
    // random masks -> execz-skipped; exactness is unconditional.
    #pragma unroll
    for (int k = 0; k < 16; ++k) {
        if (dmin[k] > 288.0f) {
            float best = dmin[k];
            int r = r0 + k;
            for (int rp = 0; rp < 256; ++rp) {
                float dr = (float)(r - rp);
                best = fminf(best, fmaf(dr, dr, tile[c * 289 + 16 + rp]));
            }
            dmin[k] = best;
        }
    }

    // block max (d2 domain; weight applied after sqrt -- monotone per slice)
    float m = 0.f;
    #pragma unroll
    for (int k = 0; k < 16; ++k) m = fmaxf(m, dmin[k]);
    #pragma unroll
    for (int off = 32; off >= 1; off >>= 1)
        m = fmaxf(m, __shfl_down(m, off, 64));
    if ((tid & 63) == 0) wm[tid >> 6] = m;
    __syncthreads();

    // cross-strip slice max: atomicMax (float-as-uint, valid: d2 >= 0) +
    // release counter; acquire-spin until all 16 strips of the slice posted.
    if (tid == 0) {
        float bmax = fmaxf(fmaxf(wm[0], wm[1]), fmaxf(wm[2], wm[3]));
        atomicMax(ctrl + slice, __float_as_uint(bmax));
        __threadfence();                                  // publish before count
        atomicAdd(ctrl + 64 + slice, 1u);
        while (__hip_atomic_load(ctrl + 64 + slice, __ATOMIC_ACQUIRE,
                                 __HIP_MEMORY_SCOPE_AGENT) < 16u) {
            __builtin_amdgcn_s_sleep(1);
        }
        sMx = __uint_as_float(__hip_atomic_load(ctrl + slice, __ATOMIC_RELAXED,
                                                __HIP_MEMORY_SCOPE_AGENT));
    }
    __syncthreads();

    // fused epilogue: out = (mx - w*sqrt(d2)) / mx  (inverted, normalized)
    int ch = slice % 3;
    float wgt = (ch == 0) ? 0.5f : ((ch == 1) ? 1.0f : 2.0f);
    float mx = wgt * __builtin_sqrtf(sMx);
    float* dst = out + (long)slice * 65536 + w0 + c;
    if (mx > 0.f) {
        float inv = 1.0f / mx;
        #pragma unroll
        for (int k = 0; k < 16; ++k)
            dst[(long)(r0 + k) * 256] = (mx - wgt * __builtin_sqrtf(dmin[k])) * inv;
    } else {
        #pragma unroll
        for (int k = 0; k < 16; ++k)
            dst[(long)(r0 + k) * 256] = wgt * __builtin_sqrtf(dmin[k]);
    }
}

extern "C" void kernel_launch(void* const* d_in, const int* in_sizes, int n_in,
                              void* d_out, int out_size, void* d_ws, size_t ws_size,
                              hipStream_t stream) {
    const float* in = (const float*)d_in[0];
    float* out = (float*)d_out;
    unsigned* ctrl = (unsigned*)d_ws;                                  // 128 uints
    unsigned long long* bits = (unsigned long long*)((char*)d_ws + 4096);  // 384 KB

    k1_bitmask<<<3072, 256, 0, stream>>>(in, bits, ctrl);   // 12288 rows, wave/row
    k2_fused<<<768, 256, 0, stream>>>(bits, out, ctrl);     // strip blocks + fused epilogue
}

// Round 2
// 101.588 us; speedup vs baseline: 1.0127x; 1.0127x over previous
//
#include <hip/hip_runtime.h>

// B=16, C=3, H=256, W=256 fp32. 48 slices of 256x256.
// out = inverted, per-slice max-normalized, per-channel-weighted exact EDT.
//
// Pipeline (2 launches, fused epilogue):
//   K1: wave per row -> four 64-bit zero-ballots per row (bitmask, 32 B/row)
//       into d_ws (+4096). Block 0 also zeroes the 128-uint control region.
//   K2f: per 16-col strip: slice bitmask (8 KB) -> LDS; each thread computes
//       g^2 for its OWN 16 contiguous rows (kept in VGPRs *and* stored to the
//       LDS tile for neighbors/fallback). Window min-plus (+-16) uses
//       register-resident own[] for the interior and only 32 LDS halo reads.
//       Per-pixel EXACT fallback (full 256-row column rescan) when windowed
//       min > 288. d2 stays in registers -> atomicMax slice max -> release
//       counter -> acquire spin -> fused epilogue writes final output only.
//       Deadlock-free: waves_per_eu(3,3) caps VGPR<=170 => >=3 blocks/CU
//       (LDS 26.7KB allows 6), grid 768 = 256 CU * 3 -> all co-resident.

#define PADV 1e30f

// ---------------- K1: row bitmask via ballots + ctrl zeroing ----------------
// One wave per row. Lane l holds cols 4l..4l+3; bz[cc] bit l = (col 4l+cc == 0).
__global__ __launch_bounds__(256) void k1_bitmask(const float* __restrict__ in,
                                                  unsigned long long* __restrict__ bits,
                                                  unsigned* __restrict__ ctrl) {
    if (blockIdx.x == 0 && threadIdx.x < 128) ctrl[threadIdx.x] = 0u;

    int row = blockIdx.x * 4 + (threadIdx.x >> 6);
    int lane = threadIdx.x & 63;
    const float4 m = ((const float4*)in)[(long)row * 64 + lane];

    unsigned long long b0 = __ballot(m.x == 0.f);
    unsigned long long b1 = __ballot(m.y == 0.f);
    unsigned long long b2 = __ballot(m.z == 0.f);
    unsigned long long b3 = __ballot(m.w == 0.f);
    if (lane == 0) {
        ulonglong4* dst = (ulonglong4*)(bits + (long)row * 4);
        ulonglong4 v; v.x = b0; v.y = b1; v.z = b2; v.w = b3;
        *dst = v;
    }
}

// ---------------- K2f: g2 + exact min-plus + fused epilogue -----------------
// Block = 256 threads = one slice's 16-col strip (grid 48*16).
// LDS: slice bitmask (256 rows x 4 ull = 8 KB) + column-major g2 tile with
// stride 289 (odd -> 2-way-max banking everywhere) and 16 pad rows each side.
__global__ __launch_bounds__(256) __attribute__((amdgpu_waves_per_eu(3, 3)))
void k2_fused(const unsigned long long* __restrict__ bits,
              float* __restrict__ out,
              unsigned* __restrict__ ctrl) {
    __shared__ unsigned long long bm[1024];   // [row*4 + cc]
    __shared__ float tile[16 * 289];
    __shared__ float wm[4];
    __shared__ float sMx;
    int bx = blockIdx.x;
    int slice = bx >> 4;
    int w0 = (bx & 15) * 16;
    int tid = threadIdx.x;

    // load slice bitmask: 1024 ull, coalesced
    {
        const unsigned long long* src = bits + (long)slice * 1024;
        #pragma unroll
        for (int i = 0; i < 4; ++i) bm[i * 256 + tid] = src[i * 256 + tid];
    }
    // pad rows of the tile
    {
        int cc = tid >> 4, i = tid & 15;
        tile[cc * 289 + i] = PADV;
        tile[cc * 289 + 272 + i] = PADV;
    }
    __syncthreads();

    int c = tid & 15;                 // column within strip
    int p = w0 + c;                   // global column 0..255
    int rg = tid >> 4;                // 0..15
    int r0 = rg * 16;                 // contiguous ownership: rows r0..r0+15

    // hoist p-dependent mask constants out of the row loop (row-invariant)
    unsigned long long mLo[4], mHi[4];
    int qv[4];
    #pragma unroll
    for (int cc = 0; cc < 4; ++cc) {
        int q = p - cc;                          // >= -3
        int qa = (q < 0) ? 0 : q;
        int tp = qa >> 2;                        // floor(q/4) for q>=0
        mLo[cc] = (q >= 0) ? (~0ull >> (63 - tp)) : 0ull;
        int tn = (q < 0) ? 0 : ((q + 3) >> 2);   // ceil(q/4)
        mHi[cc] = (tn < 64) ? (~0ull << tn) : 0ull;
        qv[cc] = q;
    }

    // g2 for own 16 contiguous rows: keep in registers AND publish to LDS.
    // (post-barrier the compiler cannot remat own[] from the tile.)
    float own[16];
    #pragma unroll
    for (int k = 0; k < 16; ++k) {
        int r = r0 + k;
        int dist = 512;               // BIG cap (H+W), matches reference
        #pragma unroll
        for (int cc = 0; cc < 4; ++cc) {
            unsigned long long M = bm[r * 4 + cc];
            unsigned long long Ml = M & mLo[cc];
            unsigned long long Mh = M & mHi[cc];
            if (Ml) dist = min(dist, qv[cc] - 4 * (63 - __builtin_clzll(Ml)));
            if (Mh) dist = min(dist, 4 * __builtin_ctzll(Mh) - qv[cc]);
        }
        float fd = (float)dist;
        float v = fd * fd;
        own[k] = v;
        tile[c * 289 + 16 + r] = v;   // bank = c + 16*rg + k (mod 32): 2-way, free
    }
    __syncthreads();

    // halo rows from LDS: rows r0-16..r0-1 and r0+16..r0+31 (32 reads total)
    float lo[16], hi[16];
    #pragma unroll
    for (int i = 0; i < 16; ++i) {
        lo[i] = tile[c * 289 + r0 + i];          // row r0-16+i (pads for rg==0)
        hi[i] = tile[c * 289 + 32 + r0 + i];     // row r0+16+i (pads for rg==15)
    }

    // window min-plus, +-o paired: min(s[k-o], s[k+o]) + o^2
    float dmin[16];
    #pragma unroll
    for (int k = 0; k < 16; ++k) dmin[k] = own[k];     // o = 0
    #pragma unroll
    for (int o = 1; o <= 16; ++o) {
        float oo = (float)(o * o);
        #pragma unroll
        for (int k = 0; k < 16; ++k) {
            int jm = k - o, jp = k + o;
            float a = (jm >= 0) ? own[jm] : lo[jm + 16];
            float b = (jp < 16) ? own[jp] : hi[jp - 16];
            dmin[k] = fminf(dmin[k], fminf(a, b) + oo);
        }
    }

    // per-pixel exact fallback: windowed min > 288 can't certify optimality
    // within +-16; rescan the full column (already in LDS). Never taken for
    // random masks -> execz-skipped; exactness is unconditional.
    #pragma unroll
    for (int k = 0; k < 16; ++k) {
        if (dmin[k] > 288.0f) {
            float best = dmin[k];
            int r = r0 + k;
            for (int rp = 0; rp < 256; ++rp) {
                float dr = (float)(r - rp);
                best = fminf(best, fmaf(dr, dr, tile[c * 289 + 16 + rp]));
            }
            dmin[k] = best;
        }
    }

    // block max (d2 domain; weight applied after sqrt -- monotone per slice)
    float m = 0.f;
    #pragma unroll
    for (int k = 0; k < 16; ++k) m = fmaxf(m, dmin[k]);
    #pragma unroll
    for (int off = 32; off >= 1; off >>= 1)
        m = fmaxf(m, __shfl_down(m, off, 64));
    if ((tid & 63) == 0) wm[tid >> 6] = m;
    __syncthreads();

    // cross-strip slice max: atomicMax (float-as-uint, valid: d2 >= 0) +
    // release counter; acquire-spin until all 16 strips of the slice posted.
    if (tid == 0) {
        float bmax = fmaxf(fmaxf(wm[0], wm[1]), fmaxf(wm[2], wm[3]));
        atomicMax(ctrl + slice, __float_as_uint(bmax));
        __threadfence();                                  // publish before count
        atomicAdd(ctrl + 64 + slice, 1u);
        while (__hip_atomic_load(ctrl + 64 + slice, __ATOMIC_ACQUIRE,
                                 __HIP_MEMORY_SCOPE_AGENT) < 16u) {
            __builtin_amdgcn_s_sleep(1);
        }
        sMx = __uint_as_float(__hip_atomic_load(ctrl + slice, __ATOMIC_RELAXED,
                                                __HIP_MEMORY_SCOPE_AGENT));
    }
    __syncthreads();

    // fused epilogue: out = (mx - w*sqrt(d2)) / mx  (inverted, normalized)
    int ch = slice % 3;
    float wgt = (ch == 0) ? 0.5f : ((ch == 1) ? 1.0f : 2.0f);
    float mx = wgt * __builtin_sqrtf(sMx);
    float* dst = out + (long)slice * 65536 + w0 + c;
    if (mx > 0.f) {
        float inv = 1.0f / mx;
        #pragma unroll
        for (int k = 0; k < 16; ++k)
            dst[(long)(r0 + k) * 256] = (mx - wgt * __builtin_sqrtf(dmin[k])) * inv;
    } else {
        #pragma unroll
        for (int k = 0; k < 16; ++k)
            dst[(long)(r0 + k) * 256] = wgt * __builtin_sqrtf(dmin[k]);
    }
}

extern "C" void kernel_launch(void* const* d_in, const int* in_sizes, int n_in,
                              void* d_out, int out_size, void* d_ws, size_t ws_size,
                              hipStream_t stream) {
    const float* in = (const float*)d_in[0];
    float* out = (float*)d_out;
    unsigned* ctrl = (unsigned*)d_ws;                                  // 128 uints
    unsigned long long* bits = (unsigned long long*)((char*)d_ws + 4096);  // 384 KB

    k1_bitmask<<<3072, 256, 0, stream>>>(in, bits, ctrl);   // 12288 rows, wave/row
    k2_fused<<<768, 256, 0, stream>>>(bits, out, ctrl);     // strip blocks + fused epilogue
}

// Round 3
// 86.589 us; speedup vs baseline: 1.1881x; 1.1732x over previous
//
#include <hip/hip_runtime.h>

// B=16, C=3, H=256, W=256 fp32. 48 slices of 256x256.
// out = inverted, per-slice max-normalized, per-channel-weighted exact EDT.
//
// Pipeline (3 launches, no atomics, no spin):
//   K1: wave per row -> four 64-bit zero-ballots per row (bitmask, 32 B/row).
//   K2: per 16-col strip: slice bitmask (8 KB) -> LDS; g^2 per thread for its
//       OWN 16 contiguous rows (registers); LDS reused (union) for the g^2
//       tile; +-16 paired window min-plus from registers + 32 LDS halo reads;
//       per-pixel EXACT fallback (full column rescan) when windowed min > 288.
//       Writes d2 -> out buffer, per-strip max -> d_ws (plain store, always).
//       LDS 18.5 KB, waves_per_eu(4) min -> VGPR<=128, 5-6 blocks/CU.
//   K3: epilogue out = (mx - w*sqrt(d2))/mx; slice max = max of 16 strip maxes.

#define PADV 1e30f

// ---------------- K1: row bitmask via ballots -------------------------------
// One wave per row. Lane l holds cols 4l..4l+3; bz[cc] bit l = (col 4l+cc == 0).
__global__ __launch_bounds__(256) void k1_bitmask(const float* __restrict__ in,
                                                  unsigned long long* __restrict__ bits) {
    int row = blockIdx.x * 4 + (threadIdx.x >> 6);
    int lane = threadIdx.x & 63;
    const float4 m = ((const float4*)in)[(long)row * 64 + lane];

    unsigned long long b0 = __ballot(m.x == 0.f);
    unsigned long long b1 = __ballot(m.y == 0.f);
    unsigned long long b2 = __ballot(m.z == 0.f);
    unsigned long long b3 = __ballot(m.w == 0.f);
    if (lane == 0) {
        ulonglong4* dst = (ulonglong4*)(bits + (long)row * 4);
        ulonglong4 v; v.x = b0; v.y = b1; v.z = b2; v.w = b3;
        *dst = v;
    }
}

// ---------------- K2: g2 + exact min-plus column pass -----------------------
// Block = 256 threads = one slice's 16-col strip (grid 48*16).
// LDS: single 18.5 KB buffer. Phase A: first 8 KB hold the slice bitmask.
// Phase B (after g2 lives in registers): same LDS holds the column-major g2
// tile, stride 289 (289%32==1 -> 2-way-max banking) with 16 pad rows each side.
__global__ __launch_bounds__(256) __attribute__((amdgpu_waves_per_eu(4)))
void k2_colpass(const unsigned long long* __restrict__ bits,
                float* __restrict__ d2out,
                float* __restrict__ stripmax) {
    __shared__ __align__(16) float tile[16 * 289];            // 18496 B (union)
    __shared__ float wm[4];
    unsigned long long* bm = (unsigned long long*)tile;       // phase-A alias

    int bx = blockIdx.x;
    int slice = bx >> 4;
    int w0 = (bx & 15) * 16;
    int tid = threadIdx.x;

    // phase A: load slice bitmask: 1024 ull, coalesced
    {
        const unsigned long long* src = bits + (long)slice * 1024;
        #pragma unroll
        for (int i = 0; i < 4; ++i) bm[i * 256 + tid] = src[i * 256 + tid];
    }
    __syncthreads();

    int c = tid & 15;                 // column within strip
    int p = w0 + c;                   // global column 0..255
    int rg = tid >> 4;                // 0..15
    int r0 = rg * 16;                 // contiguous ownership: rows r0..r0+15

    // hoist p-dependent mask constants out of the row loop (row-invariant)
    unsigned long long mLo[4], mHi[4];
    int qv[4];
    #pragma unroll
    for (int cc = 0; cc < 4; ++cc) {
        int q = p - cc;                          // >= -3
        int qa = (q < 0) ? 0 : q;
        int tp = qa >> 2;                        // floor(q/4) for q>=0
        mLo[cc] = (q >= 0) ? (~0ull >> (63 - tp)) : 0ull;
        int tn = (q < 0) ? 0 : ((q + 3) >> 2);   // ceil(q/4)
        mHi[cc] = (tn < 64) ? (~0ull << tn) : 0ull;
        qv[cc] = q;
    }

    // g2 for own 16 contiguous rows -> registers. Row order staggered by rg so
    // the 4 rgroups of a wave read rows with distinct row%4 -> b128 reads hit
    // bank sets {0,8,16,24}: conflict-free, broadcast across the 16 columns.
    const ulonglong2* bmv = (const ulonglong2*)bm;
    float own[16];
    #pragma unroll
    for (int k = 0; k < 16; ++k) {
        int kk = (k + rg) & 15;
        int r = r0 + kk;
        ulonglong2 wa = bmv[r * 2];
        ulonglong2 wb = bmv[r * 2 + 1];
        unsigned long long M[4] = { wa.x, wa.y, wb.x, wb.y };
        int dist = 512;               // BIG cap (H+W), matches reference
        #pragma unroll
        for (int cc = 0; cc < 4; ++cc) {
            unsigned long long Ml = M[cc] & mLo[cc];
            unsigned long long Mh = M[cc] & mHi[cc];
            if (Ml) dist = min(dist, qv[cc] - 4 * (63 - __builtin_clzll(Ml)));
            if (Mh) dist = min(dist, 4 * __builtin_ctzll(Mh) - qv[cc]);
        }
        float fd = (float)dist;
        own[kk] = fd * fd;
    }
    __syncthreads();                  // bm dead from here on

    // phase B: publish g2 tile (+pads) into the SAME LDS
    {
        int cc = tid >> 4, i = tid & 15;
        tile[cc * 289 + i] = PADV;
        tile[cc * 289 + 272 + i] = PADV;
    }
    #pragma unroll
    for (int k = 0; k < 16; ++k)
        tile[c * 289 + 16 + r0 + k] = own[k];   // 2-way bank alias: free
    __syncthreads();

    // halo rows from LDS: rows r0-16..r0-1 and r0+16..r0+31 (32 reads total)
    float lo[16], hi[16];
    #pragma unroll
    for (int i = 0; i < 16; ++i) {
        lo[i] = tile[c * 289 + r0 + i];          // row r0-16+i (pads for rg==0)
        hi[i] = tile[c * 289 + 32 + r0 + i];     // row r0+16+i (pads for rg==15)
    }

    // window min-plus, +-o paired: min(s[k-o], s[k+o]) + o^2
    float dmin[16];
    #pragma unroll
    for (int k = 0; k < 16; ++k) dmin[k] = own[k];     // o = 0
    #pragma unroll
    for (int o = 1; o <= 16; ++o) {
        float oo = (float)(o * o);
        #pragma unroll
        for (int k = 0; k < 16; ++k) {
            int jm = k - o, jp = k + o;
            float a = (jm >= 0) ? own[jm] : lo[jm + 16];
            float b = (jp < 16) ? own[jp] : hi[jp - 16];
            dmin[k] = fminf(dmin[k], fminf(a, b) + oo);
        }
    }

    // per-pixel exact fallback: windowed min > 288 can't certify optimality
    // within +-16; rescan the full column (already in LDS). Never taken for
    // random masks -> execz-skipped; exactness is unconditional.
    #pragma unroll
    for (int k = 0; k < 16; ++k) {
        if (dmin[k] > 288.0f) {
            float best = dmin[k];
            int r = r0 + k;
            for (int rp = 0; rp < 256; ++rp) {
                float dr = (float)(r - rp);
                best = fminf(best, fmaf(dr, dr, tile[c * 289 + 16 + rp]));
            }
            dmin[k] = best;
        }
    }

    // write back d2, track block max
    float* dst = d2out + (long)slice * 65536 + w0 + c;
    float m = 0.f;
    #pragma unroll
    for (int k = 0; k < 16; ++k) {
        dst[(long)(r0 + k) * 256] = dmin[k];
        m = fmaxf(m, dmin[k]);
    }
    #pragma unroll
    for (int off = 32; off >= 1; off >>= 1)
        m = fmaxf(m, __shfl_down(m, off, 64));
    if ((tid & 63) == 0) wm[tid >> 6] = m;
    __syncthreads();
    if (tid == 0)
        stripmax[bx] = fmaxf(fmaxf(wm[0], wm[1]), fmaxf(wm[2], wm[3]));
}

// ---------------- K3: epilogue ---------------------------------------------
// 64 blocks per slice; each block reduces the slice's 16 strip maxes once.
__global__ __launch_bounds__(256) void k3_final(float* __restrict__ out,
                                                const float* __restrict__ stripmax) {
    __shared__ float sMx;
    int tid = threadIdx.x;
    int idx4 = blockIdx.x * 256 + tid;    // float4 index, 786432 total
    int slice = blockIdx.x >> 6;          // 64 blocks per slice
    if (tid < 16) {
        float v = stripmax[slice * 16 + tid];
        #pragma unroll
        for (int off = 8; off >= 1; off >>= 1) v = fmaxf(v, __shfl_down(v, off, 64));
        if (tid == 0) sMx = v;
    }
    __syncthreads();

    int c = slice % 3;
    float wgt = (c == 0) ? 0.5f : ((c == 1) ? 1.0f : 2.0f);
    float mx = wgt * __builtin_sqrtf(sMx);

    float4 d2 = ((float4*)out)[idx4];
    float4 r;
    if (mx > 0.f) {
        float inv = 1.0f / mx;
        r.x = (mx - wgt * __builtin_sqrtf(d2.x)) * inv;
        r.y = (mx - wgt * __builtin_sqrtf(d2.y)) * inv;
        r.z = (mx - wgt * __builtin_sqrtf(d2.z)) * inv;
        r.w = (mx - wgt * __builtin_sqrtf(d2.w)) * inv;
    } else {
        r.x = wgt * __builtin_sqrtf(d2.x);
        r.y = wgt * __builtin_sqrtf(d2.y);
        r.z = wgt * __builtin_sqrtf(d2.z);
        r.w = wgt * __builtin_sqrtf(d2.w);
    }
    ((float4*)out)[idx4] = r;
}

extern "C" void kernel_launch(void* const* d_in, const int* in_sizes, int n_in,
                              void* d_out, int out_size, void* d_ws, size_t ws_size,
                              hipStream_t stream) {
    const float* in = (const float*)d_in[0];
    float* out = (float*)d_out;
    float* stripmax = (float*)d_ws;                                   // 768 floats
    unsigned long long* bits = (unsigned long long*)((char*)d_ws + 4096);  // 384 KB

    k1_bitmask<<<3072, 256, 0, stream>>>(in, bits);       // 12288 rows, wave/row
    k2_colpass<<<768, 256, 0, stream>>>(bits, out, stripmax);
    k3_final<<<3072, 256, 0, stream>>>(out, stripmax);    // 786432 float4
}

// Round 5
// 80.635 us; speedup vs baseline: 1.2758x; 1.0738x over previous
//
#include <hip/hip_runtime.h>

// B=16, C=3, H=256, W=256 fp32. 48 slices of 256x256.
// out = inverted, per-slice max-normalized, per-channel-weighted exact EDT.
//
// Pipeline (3 launches):
//   K1: wave per row. Ballots give every lane the full 256-col zero-mask in
//       4 ulls; each lane computes EXACT 1D nearest-zero distance for its 4
//       cols fully in registers (compile-time residue unroll + prefix
//       max/min), writes g as u16 row-major (6.3 MB, coalesced). No LDS.
//   K2: block = 16 cols x 128 rows (half-slice strip), 1536 blocks -> 6
//       waves/SIMD. Loads g strip (+-16-row halo) -> LDS (col-major, d^2 as
//       float, stride 161), one barrier, then +-16 window min-plus from
//       registers (own 8 rows + 32 halo reads). Per-pixel EXACT fallback
//       (full 256-row column scan from global g) when windowed min > 288
//       (|o|>=17 candidates are >= 289). Writes d2 -> out, block max -> ws.
//   K3: epilogue out = (mx - w*sqrt(d2))/mx; slice max = max of 32 blk maxes.

#define PADV 1e30f

// ---------------- K1: register 1D EDT via ballots ---------------------------
// Lane l holds cols 4l..4l+3. b[cc] bit j = (col 4j+cc == 0).
// Left target for col p=4l+ci, residue cc: j <= l - (ci<cc); right: j >= l + (ci>cc).
__global__ __launch_bounds__(256) void k1_g16(const float* __restrict__ in,
                                              unsigned short* __restrict__ g) {
    int row = blockIdx.x * 4 + (threadIdx.x >> 6);
    int lane = threadIdx.x & 63;
    const float4 m = ((const float4*)in)[(long)row * 64 + lane];

    unsigned long long b[4];
    b[0] = __ballot(m.x == 0.f);
    b[1] = __ballot(m.y == 0.f);
    b[2] = __ballot(m.z == 0.f);
    b[3] = __ballot(m.w == 0.f);

    unsigned long long loP = ~0ull >> (63 - lane);  // bits 0..lane
    unsigned long long loM = loP >> 1;              // bits 0..lane-1 (0 if lane==0)
    unsigned long long hiP = ~0ull << lane;         // bits lane..63
    unsigned long long hiM = hiP << 1;              // bits lane+1..63 (0 if lane==63)

    int LP[4], LM[4], RP[4], RM[4];
    #pragma unroll
    for (int cc = 0; cc < 4; ++cc) {
        unsigned long long mlp = b[cc] & loP;
        unsigned long long mlm = b[cc] & loM;
        unsigned long long mhp = b[cc] & hiP;
        unsigned long long mhm = b[cc] & hiM;
        LP[cc] = mlp ? 4 * (63 - __builtin_clzll(mlp)) + cc : -1000;  // col of nearest-left zero
        LM[cc] = mlm ? 4 * (63 - __builtin_clzll(mlm)) + cc : -1000;
        RP[cc] = mhp ? 4 * __builtin_ctzll(mhp) + cc : 2000;          // col of nearest-right zero
        RM[cc] = mhm ? 4 * __builtin_ctzll(mhm) + cc : 2000;
    }
    // colL(ci) = max( LP[cc] for cc<=ci, LM[cc] for cc>ci )
    int qp1 = max(LP[0], LP[1]);
    int qp2 = max(qp1, LP[2]);
    int qp3 = max(qp2, LP[3]);
    int sm3 = LM[3];
    int sm2 = max(LM[2], sm3);
    int sm1 = max(LM[1], sm2);
    int colL0 = max(LP[0], sm1);
    int colL1 = max(qp1, sm2);
    int colL2 = max(qp2, sm3);
    int colL3 = qp3;
    // colR(ci) = min( RM[cc] for cc<ci, RP[cc] for cc>=ci )
    int sp2 = min(RP[2], RP[3]);
    int sp1 = min(RP[1], sp2);
    int sp0 = min(RP[0], sp1);
    int pm0 = RM[0];
    int pm1 = min(pm0, RM[1]);
    int pm2 = min(pm1, RM[2]);
    int colR0 = sp0;
    int colR1 = min(pm0, sp1);
    int colR2 = min(pm1, sp2);
    int colR3 = min(pm2, RP[3]);

    int p0 = lane * 4;
    int d0 = min(min(p0 - colL0, colR0 - p0), 512);          // cap = BIG = H+W
    int d1 = min(min(p0 + 1 - colL1, colR1 - p0 - 1), 512);
    int d2 = min(min(p0 + 2 - colL2, colR2 - p0 - 2), 512);
    int d3 = min(min(p0 + 3 - colL3, colR3 - p0 - 3), 512);

    ushort4 v;
    v.x = (unsigned short)d0; v.y = (unsigned short)d1;
    v.z = (unsigned short)d2; v.w = (unsigned short)d3;
    ((ushort4*)(g + (long)row * 256))[lane] = v;             // coalesced 512 B/wave
}

// ---------------- K2: column min-plus over g --------------------------------
// Grid 1536 = 48 slices x 16 col-strips x 2 row-halves. 256 threads:
// c = tid&15 (column), rg = tid>>4 (8-row group). LDS tile: [16 cols][161]
// (160 rows = 128 owned + 16 halo each side; stride 161 -> 2-way max banking).
__global__ __launch_bounds__(256) __attribute__((amdgpu_waves_per_eu(4)))
void k2_colpass(const unsigned short* __restrict__ g,
                float* __restrict__ d2out,
                float* __restrict__ stripmax) {
    __shared__ float tile[16 * 161];   // 10304 B
    __shared__ float wm[4];
    int bx = blockIdx.x;
    int slice = bx >> 5;
    int sub = bx & 31;
    int strip = sub >> 1;
    int half = sub & 1;                // adjacent blocks share a strip (L2 reuse)
    int w0 = strip * 16;
    int base = half * 128;
    int tid = threadIdx.x;

    // fill tile rows [base-16, base+143]; u16 d -> float d^2 on the fly
    if (tid < 160) {
        int r = base - 16 + tid;
        if (r >= 0 && r < 256) {
            const uint4* src = (const uint4*)(g + (long)slice * 65536 + (long)r * 256 + w0);
            #pragma unroll
            for (int j = 0; j < 2; ++j) {
                uint4 q = src[j];
                unsigned vv[4] = {q.x, q.y, q.z, q.w};
                #pragma unroll
                for (int e = 0; e < 4; ++e) {
                    float dl = (float)(vv[e] & 0xffffu);
                    float dh = (float)(vv[e] >> 16);
                    int col = j * 8 + e * 2;
                    tile[col * 161 + tid] = dl * dl;         // bank (col+tid)%32: 2-way
                    tile[(col + 1) * 161 + tid] = dh * dh;
                }
            }
        } else {
            #pragma unroll
            for (int cc = 0; cc < 16; ++cc) tile[cc * 161 + tid] = PADV;
        }
    }
    __syncthreads();

    int c = tid & 15;
    int rg = tid >> 4;
    int i0 = 16 + rg * 8;              // tile index of first owned row
    float own[8], lo[16], hi[16];
    #pragma unroll
    for (int k = 0; k < 8; ++k) own[k] = tile[c * 161 + i0 + k];
    #pragma unroll
    for (int i = 0; i < 16; ++i) {
        lo[i] = tile[c * 161 + i0 - 16 + i];   // rows r0-16..r0-1
        hi[i] = tile[c * 161 + i0 + 8 + i];    // rows r0+8..r0+23
    }

    // window min-plus, +-o paired, all indices compile-time
    float dmin[8];
    #pragma unroll
    for (int k = 0; k < 8; ++k) dmin[k] = own[k];
    #pragma unroll
    for (int o = 1; o <= 16; ++o) {
        float oo = (float)(o * o);
        #pragma unroll
        for (int k = 0; k < 8; ++k) {
            int jm = k - o, jp = k + o;
            float a = (jm >= 0) ? own[jm] : lo[jm + 16];
            float b = (jp < 8) ? own[jp] : hi[jp - 8];
            dmin[k] = fminf(dmin[k], fminf(a, b) + oo);
        }
    }

    int p = w0 + c;
    int r0 = base + rg * 8;
    // exact fallback: windowed min > 288 can't certify +-16 optimality; rescan
    // the full column from global g. Never taken for random masks (execz).
    #pragma unroll
    for (int k = 0; k < 8; ++k) {
        if (dmin[k] > 288.0f) {
            float best = dmin[k];
            int r = r0 + k;
            const unsigned short* col = g + (long)slice * 65536 + p;
            for (int rp = 0; rp < 256; ++rp) {
                float gv = (float)col[rp * 256];
                float dr = (float)(r - rp);
                best = fminf(best, fmaf(dr, dr, gv * gv));
            }
            dmin[k] = best;
        }
    }

    // write d2 + block max
    float* dst = d2out + (long)slice * 65536 + w0 + c;
    float mmax = 0.f;
    #pragma unroll
    for (int k = 0; k < 8; ++k) {
        dst[(long)(r0 + k) * 256] = dmin[k];
        mmax = fmaxf(mmax, dmin[k]);
    }
    #pragma unroll
    for (int off = 32; off >= 1; off >>= 1)
        mmax = fmaxf(mmax, __shfl_down(mmax, off, 64));
    if ((tid & 63) == 0) wm[tid >> 6] = mmax;
    __syncthreads();
    if (tid == 0)
        stripmax[bx] = fmaxf(fmaxf(wm[0], wm[1]), fmaxf(wm[2], wm[3]));
}

// ---------------- K3: epilogue ---------------------------------------------
// 64 blocks per slice; each block reduces the slice's 32 block maxes once.
__global__ __launch_bounds__(256) void k3_final(float* __restrict__ out,
                                                const float* __restrict__ stripmax) {
    __shared__ float sMx;
    int tid = threadIdx.x;
    int idx4 = blockIdx.x * 256 + tid;    // float4 index, 786432 total
    int slice = blockIdx.x >> 6;          // 64 blocks per slice
    if (tid < 32) {
        float v = stripmax[slice * 32 + tid];
        #pragma unroll
        for (int off = 16; off >= 1; off >>= 1) v = fmaxf(v, __shfl_down(v, off, 64));
        if (tid == 0) sMx = v;
    }
    __syncthreads();

    int c = slice % 3;
    float wgt = (c == 0) ? 0.5f : ((c == 1) ? 1.0f : 2.0f);
    float mx = wgt * __builtin_sqrtf(sMx);

    float4 d2 = ((float4*)out)[idx4];
    float4 r;
    if (mx > 0.f) {
        float inv = 1.0f / mx;
        r.x = (mx - wgt * __builtin_sqrtf(d2.x)) * inv;
        r.y = (mx - wgt * __builtin_sqrtf(d2.y)) * inv;
        r.z = (mx - wgt * __builtin_sqrtf(d2.z)) * inv;
        r.w = (mx - wgt * __builtin_sqrtf(d2.w)) * inv;
    } else {
        r.x = wgt * __builtin_sqrtf(d2.x);
        r.y = wgt * __builtin_sqrtf(d2.y);
        r.z = wgt * __builtin_sqrtf(d2.z);
        r.w = wgt * __builtin_sqrtf(d2.w);
    }
    ((float4*)out)[idx4] = r;
}

extern "C" void kernel_launch(void* const* d_in, const int* in_sizes, int n_in,
                              void* d_out, int out_size, void* d_ws, size_t ws_size,
                              hipStream_t stream) {
    const float* in = (const float*)d_in[0];
    float* out = (float*)d_out;
    float* stripmax = (float*)d_ws;                                   // 1536 floats
    unsigned short* g = (unsigned short*)((char*)d_ws + 8192);        // 6.29 MB

    k1_g16<<<3072, 256, 0, stream>>>(in, g);              // 12288 rows, wave/row
    k2_colpass<<<1536, 256, 0, stream>>>(g, out, stripmax);
    k3_final<<<3072, 256, 0, stream>>>(out, stripmax);    // 786432 float4
}